// Round 6
// baseline (163.100 us; speedup 1.0000x reference)
//
#include <hip/hip_runtime.h>
#include <stdint.h>
#include <stddef.h>

// RadialCTC: cosine logits (norm_scale=32) -> log_softmax -> CTC(sum).
// Strategy: never materialize the (16384 x 1296) logits. GEMM (f16 MFMA)
// computes per-row sum(exp(logit)) fused in the epilogue; label log-probs via
// small f16 MFMA gather-GEMM; CTC alpha recursion one wave per sample.
// R9: linear f64 + pow2 renorm ctc. R11: XOR channel-slot LDS swizzle (gemm).
// R12: 9 -> 4 dispatches: NO CHANGE -> per-node gap ~= 0.
// R14: log2(sumexp) factored out (Msum); gather independent of gemm (-2us).
// R15 FAILED (312us): agent-scope acquire spin -> buffer_inv storms killed L2.
// R16 (159us): per-sample gather+ctc fused in-block, zero cross-block sync.
//   Counters: mega 62.6us, MfmaUtil 14.7% -> MFMA busy 9.2us = workload floor.
//   Total = 2 fills (88, harness) + prep ~10 + mega 62.6 + final ~3.
//   mega's critical path = the 32 gather+ctc blocks (gather ~28 via
//   2-barrier/kb LDS loop + ctc ~33), NOT the gemm (~44).
// R17 (this round): (a) register-direct gather: MFMA frags loaded per-lane
//   straight from global (row=lane&15, k=hi*8) - no LDS/barriers/vmcnt in the
//   kb loop, compiler pipelines; adjacent kb share cachelines -> L1-hot.
//   (b) 4-chunk pipeline: waves 1-3 produce lp chunk c (48/48/32 t-rows each)
//   then barrier, wave 0 runs ctc on chunk c-1 concurrently. Chain ~= 3 +
//   3*max(3,7.5) + 7.5 ~= 33-38us < gemm 44 -> mega becomes gemm-bound.
//   Exactly 4 barriers/block both paths; LDS back to 16KB.

typedef _Float16 f16;
typedef _Float16 f16x8 __attribute__((ext_vector_type(8)));
typedef float f32x4 __attribute__((ext_vector_type(4)));
typedef __attribute__((address_space(1))) void* as1_void_ptr;
typedef __attribute__((address_space(3))) void* as3_void_ptr;

#define TT 512
#define NN 32
#define CC 1296
#define DD 512
#define SS 30
#define CP 1408   // C padded to 11*128 for GEMM tiling (pad rows are zero)
#define LL 61     // 2*S+1 CTC states
#define NORM_SCALE 32.0f
#define LOG2E 1.4426950408889634f
#define LN2   0.6931471805599453f

#define PREP_WBLK (CP / 16)            // 88 c-tiles of 16 (covers pad -> zeros)
#define PREP_ZBLK 16                   // 16 blocks zero sumexp
#define PREP_FBLK (TT * NN / 4)        // 4096 fnorm blocks (4 rows each)

#define GEMM_BLK ((TT * NN / 128) * (CP / 128))   // 128*11 = 1408
#define MEGA_GC  NN                                // 32 gather+ctc blocks
#define MEGA_BLK (MEGA_GC + GEMM_BLK)              // 1440

__device__ __forceinline__ float fexp2(float x) { return __builtin_amdgcn_exp2f(x); }
__device__ __forceinline__ float flog2(float x) { return __builtin_amdgcn_logf(x); }

// whole-wave shift-right-by-1 of a double (two 32-bit DPPs, ctrl 0x138 =
// WAVE_SHR1). Lane 0 receives +0.0.
__device__ __forceinline__ double dpp_sr1_zero64(double x) {
    long long b = __double_as_longlong(x);
    int lo = (int)(b & 0xFFFFFFFFLL);
    int hi = (int)(b >> 32);
    int lo2 = __builtin_amdgcn_update_dpp(0, lo, 0x138, 0xF, 0xF, false);
    int hi2 = __builtin_amdgcn_update_dpp(0, hi, 0x138, 0xF, 0xF, false);
    return __longlong_as_double(((long long)hi2 << 32) |
                                (unsigned long long)(unsigned int)lo2);
}
// one level of DPP row-shr int max (identity 0; operands are >=0 hi-words)
template <int CTRL>
__device__ __forceinline__ int dpp_imax_level(int m) {
    int t = __builtin_amdgcn_update_dpp(0, m, CTRL, 0xF, 0xF, false);
    return m > t ? m : t;
}

// ---- fused prep: W column-norm + transpose to f16 (atomic-free, per-block
//      column ownership), feats row-normalize -> f16, sumexp zeroing. ----
__global__ __launch_bounds__(256) void prep_kernel(const float* __restrict__ W,
                                                   const float* __restrict__ feats,
                                                   f16* __restrict__ wt,
                                                   f16* __restrict__ fn,
                                                   float* __restrict__ sumexp) {
    int bx = blockIdx.x, tid = threadIdx.x;
    if (bx < PREP_WBLK) {
        // ---- W-prep: this block owns 16 columns c0..c0+15 ----
        __shared__ float red[256];
        __shared__ float rqs[16];
        int c0 = bx * 16;
        int cl = tid & 15, dg = tid >> 4;
        int c = c0 + cl;
        float ss = 0.f;
        if (c < CC) {
            for (int d = dg; d < DD; d += 16) {
                float v = W[(size_t)d * CC + c];
                ss += v * v;
            }
        }
        red[tid] = ss;
        __syncthreads();
        if (tid < 16) {
            float s2 = 0.f;
            #pragma unroll
            for (int k = 0; k < 16; ++k) s2 += red[tid + 16 * k];
            rqs[tid] = rsqrtf(s2);
        }
        __syncthreads();
        // write wt[c][d] (f16), 16 consecutive-d lanes per c; W re-reads hit L1
        int c_loc = tid >> 4, dl = tid & 15;
        int cc = c0 + c_loc;
        float rq = rqs[c_loc];
        #pragma unroll 4
        for (int it = 0; it < 32; ++it) {
            int d = dl + it * 16;
            float v = (cc < CC) ? W[(size_t)d * CC + cc] * rq : 0.f;
            wt[(size_t)cc * DD + d] = (f16)v;
        }
    } else if (bx < PREP_WBLK + PREP_ZBLK) {
        int zb = bx - PREP_WBLK;
        float4 z = {0.f, 0.f, 0.f, 0.f};
        ((float4*)sumexp)[zb * 256 + tid] = z;   // 16*256*16B = 64KB
    } else {
        // ---- fnorm: one wave per feats row ----
        int fb = bx - PREP_WBLK - PREP_ZBLK;
        int wv = (fb * 256 + tid) >> 6;  // row id, 0..16383
        int lane = tid & 63;
        const float4* src = (const float4*)(feats + (size_t)wv * DD) + lane * 2;
        float4 a = src[0], b = src[1];
        float ss = a.x*a.x + a.y*a.y + a.z*a.z + a.w*a.w
                 + b.x*b.x + b.y*b.y + b.z*b.z + b.w*b.w;
        #pragma unroll
        for (int off = 32; off; off >>= 1) ss += __shfl_xor(ss, off);
        float r = rsqrtf(ss);
        f16x8 o;
        o[0]=(f16)(a.x*r); o[1]=(f16)(a.y*r); o[2]=(f16)(a.z*r); o[3]=(f16)(a.w*r);
        o[4]=(f16)(b.x*r); o[5]=(f16)(b.y*r); o[6]=(f16)(b.z*r); o[7]=(f16)(b.w*r);
        *(f16x8*)(fn + (size_t)wv * DD + lane * 8) = o;
    }
}

// ---- gather wave (register-direct, barrier-free kb loop): computes its NT
//      16-row t-tiles of lp for each of 4 chunks, barrier after each chunk.
//      MFMA frag layout: A row=lane&15, k=(lane>>4)*8+e -> direct 16B loads. ----
template <int NT>
__device__ __forceinline__ void gather_wave(const f16* __restrict__ A,
                                            const f16* __restrict__ B,
                                            const int* __restrict__ labels,
                                            float* __restrict__ lp_lab,
                                            int n, int rbase, int lane) {
    int lm = lane & 15, hi = lane >> 4;
    int cls0 = (lm == 0) ? 0 : labels[n * SS + lm - 1];       // j = lm
    int cls1 = (lm >= 15) ? 0 : labels[n * SS + lm + 15];     // j = 16+lm
    const f16* pb0 = B + (size_t)cls0 * DD + hi * 8;
    const f16* pb1 = B + (size_t)cls1 * DD + hi * 8;
    const f16* pa0 = A + ((size_t)(rbase + lm) * NN + n) * DD + hi * 8;
    for (int c = 0; c < 4; ++c) {
        f32x4 acc[NT][2];
        #pragma unroll
        for (int i = 0; i < NT; ++i) {
            acc[i][0] = (f32x4){0.f, 0.f, 0.f, 0.f};
            acc[i][1] = (f32x4){0.f, 0.f, 0.f, 0.f};
        }
        const f16* pac = pa0 + (size_t)c * 128 * NN * DD;
        for (int kb = 0; kb < 16; ++kb) {
            f16x8 bf0 = *(const f16x8*)(pb0 + kb * 32);
            f16x8 bf1 = *(const f16x8*)(pb1 + kb * 32);
            #pragma unroll
            for (int i = 0; i < NT; ++i) {
                f16x8 af = *(const f16x8*)(pac + (size_t)(i * 16) * NN * DD + kb * 32);
                acc[i][0] = __builtin_amdgcn_mfma_f32_16x16x32_f16(af, bf0, acc[i][0], 0, 0, 0);
                acc[i][1] = __builtin_amdgcn_mfma_f32_16x16x32_f16(af, bf1, acc[i][1], 0, 0, 0);
            }
        }
        // raw scaled logits (no ls2: factored into final Msum); C/D row=hi*4+r
        #pragma unroll
        for (int i = 0; i < NT; ++i) {
            #pragma unroll
            for (int jn = 0; jn < 2; ++jn) {
                int jc = jn * 16 + lm;
                if (jc >= 31) continue;
                float4 o;
                o.x = acc[i][jn][0] * (NORM_SCALE * LOG2E);
                o.y = acc[i][jn][1] * (NORM_SCALE * LOG2E);
                o.z = acc[i][jn][2] * (NORM_SCALE * LOG2E);
                o.w = acc[i][jn][3] * (NORM_SCALE * LOG2E);
                *(float4*)&lp_lab[((size_t)n * 31 + jc) * TT
                                  + c * 128 + rbase + i * 16 + hi * 4] = o;
            }
        }
        __syncthreads();   // publish chunk c (barrier c)
    }
}

// ---- mega: blocks 0..31 = chunk-pipelined gather(waves1-3)+ctc(wave0);
//      blocks 32..1439 = gemm+sumexp (16KB LDS, XOR channel-slot swizzle). ----
__global__ __launch_bounds__(256) void mega_kernel(const f16* __restrict__ A,
                                                   const f16* __restrict__ B,
                                                   const int* __restrict__ labels,
                                                   const int* __restrict__ in_lens,
                                                   const int* __restrict__ lab_lens,
                                                   float* __restrict__ sumexp,
                                                   float* __restrict__ lp_lab,
                                                   double* __restrict__ part) {
    __shared__ __align__(16) f16 sm[8192];   // 16 KB (gemm only)
    int bx = blockIdx.x;
    int tid = threadIdx.x;
    int w = tid >> 6, lane = tid & 63;
    int lm = lane & 15, hi = lane >> 4;
    int sw = (lm >> 1) & 3;                // fragment-read channel swizzle

    if (bx >= MEGA_GC) {
        // ================= GEMM section (identical math since R14) ==========
        int j = bx - MEGA_GC;
        int bm = j & 127, bn = j >> 7;         // 1408 = 128 * 11
        int wm = w >> 1, wn = w & 1;           // 2x2 wave grid -> 64x64 per wave
        f32x4 acc[4][4];
        f32x4 zero = {0.f, 0.f, 0.f, 0.f};
        #pragma unroll
        for (int i = 0; i < 4; ++i)
            #pragma unroll
            for (int jj = 0; jj < 4; ++jj) acc[i][jj] = zero;

        for (int kb = 0; kb < 16; ++kb) {      // K=512, BK=32 (one MFMA K-step)
            #pragma unroll
            for (int p = 0; p < 2; ++p) {
                int s = p * 256 + tid;         // segment id, 16B each; 512 segs/tile
                int row = s >> 2;
                int ch = (s & 3) ^ ((row >> 1) & 3);   // swizzled source channel
                const f16* ga = A + (size_t)(bm * 128 + row) * DD + kb * 32 + ch * 8;
                const f16* gb = B + (size_t)(bn * 128 + row) * DD + kb * 32 + ch * 8;
                // LDS dest = wave-uniform base + lane*16 (contiguous, required)
                __builtin_amdgcn_global_load_lds((as1_void_ptr)ga,
                    (as3_void_ptr)&sm[(p * 256 + w * 64) * 8], 16, 0, 0);
                __builtin_amdgcn_global_load_lds((as1_void_ptr)gb,
                    (as3_void_ptr)&sm[4096 + (p * 256 + w * 64) * 8], 16, 0, 0);
            }
            __syncthreads();
            f16x8 af[4], bf[4];
            #pragma unroll
            for (int i = 0; i < 4; ++i)
                af[i] = *(const f16x8*)&sm[(wm * 64 + i * 16 + lm) * 32 + (hi ^ sw) * 8];
            #pragma unroll
            for (int jj = 0; jj < 4; ++jj)
                bf[jj] = *(const f16x8*)&sm[4096 + (wn * 64 + jj * 16 + lm) * 32 + (hi ^ sw) * 8];
            #pragma unroll
            for (int i = 0; i < 4; ++i)
                #pragma unroll
                for (int jj = 0; jj < 4; ++jj)
                    acc[i][jj] = __builtin_amdgcn_mfma_f32_16x16x32_f16(af[i], bf[jj], acc[i][jj], 0, 0, 0);
            __syncthreads();
        }
        // epilogue: per-row sum of exp(32*logit) over this block's 128 columns
        #pragma unroll
        for (int i = 0; i < 4; ++i) {
            float rs[4] = {0.f, 0.f, 0.f, 0.f};
            #pragma unroll
            for (int jj = 0; jj < 4; ++jj) {
                int c = bn * 128 + wn * 64 + jj * 16 + lm;   // C/D: col = lane&15
                bool ok = (c < CC);
                #pragma unroll
                for (int r = 0; r < 4; ++r)
                    rs[r] += ok ? fexp2(acc[i][jj][r] * (NORM_SCALE * LOG2E)) : 0.f;
            }
            #pragma unroll
            for (int off = 1; off < 16; off <<= 1) {        // sum over 16 cols
                #pragma unroll
                for (int r = 0; r < 4; ++r) rs[r] += __shfl_xor(rs[r], off);
            }
            if (lm == 0) {
                int rowb = bm * 128 + wm * 64 + i * 16 + hi * 4;  // row = quad*4+reg
                #pragma unroll
                for (int r = 0; r < 4; ++r) atomicAdd(&sumexp[rowb + r], rs[r]);
            }
        }
        return;
    }

    // ================= gather + ctc section (block n = bx) ==================
    int n = bx;
    if (w > 0) {
        // waves 1-3: produce lp chunks (48/48/32 t-rows per chunk), 4 barriers
        if (w < 3) gather_wave<3>(A, B, labels, lp_lab, n, (w - 1) * 48, lane);
        else       gather_wave<2>(A, B, labels, lp_lab, n, 96, lane);
        return;
    }

    // wave 0: ctc, pipelined one chunk behind the producers (4 barriers)
    int s = lane;            // 64 lanes; states 0..60 valid
    bool valid = s < LL;
    int ext = (valid && (s & 1)) ? labels[n * SS + (s >> 1)] : 0;
    int jmap = (valid && (s & 1)) ? ((s >> 1) + 1) : 0;   // state -> class slot
    int ext2 = __shfl_up(ext, 2);
    double skipd = ((s >= 2) && valid && (ext != ext2)) ? 1.0 : 0.0;
    int Tin = in_lens[n];    // wave-uniform; freeze == stop at t = Tin-1
    const float4* g4 = (const float4*)(lp_lab + ((size_t)n * 31 + jmap) * TT);

    __syncthreads();         // barrier 0: chunk 0 (t=0..127) published
    float4 cur = g4[0];
    float4 nxt = g4[1];
    float4 nx2 = g4[2];
    double beta = (s <= 1) ? (double)fexp2(cur.x) : 0.0;
    int Mi = 0;              // running log2 scale: alpha_raw = log2(beta) + Mi

    auto stepL = [&](float lp) {
        double P = (double)fexp2(lp);      // |lp| <= ~46.2: f32-safe
        double b1 = dpp_sr1_zero64(beta);
        double b2 = dpp_sr1_zero64(b1);
        beta = (beta + b1 + b2 * skipd) * P;
    };
    auto renorm = [&]() {
        int h = (int)(__double_as_longlong(beta) >> 32);  // beta>=0: monotone
        h = dpp_imax_level<0x111>(h);        // row_shr:1
        h = dpp_imax_level<0x112>(h);        // row_shr:2
        h = dpp_imax_level<0x114>(h);        // row_shr:4
        h = dpp_imax_level<0x118>(h);        // row_shr:8 -> row max 15/31/47/63
        int r0 = __builtin_amdgcn_readlane(h, 15);
        int r1 = __builtin_amdgcn_readlane(h, 31);
        int r2 = __builtin_amdgcn_readlane(h, 47);
        int r3 = __builtin_amdgcn_readlane(h, 63);
        int mx = max(max(r0, r1), max(r2, r3));
        int e11 = mx >> 20;                  // biased 11-bit exponent
        double scale = __longlong_as_double((long long)(2046 - e11) << 52);
        beta *= scale;
        Mi += e11 - 1023;
    };

    // group 0: t = 1..3 (Tin >= 481, always full)
    stepL(cur.y); stepL(cur.z); stepL(cur.w);
    renorm();
    int remaining = Tin - 4;   // steps left (total steps = Tin-1)
    int g = 1;
    // chunk c covers groups [32c, 32c+32); chunks 0..2 always full (Tin>=481).
    // Cross-chunk prefetch reads stale data that is ALWAYS discarded (cur/nxt/
    // nx2 reloaded fresh after each barrier).
    for (int c = 0; c < 4; ++c) {
        if (c > 0) {
            __syncthreads();                 // barrier c: chunk c published
            nxt = g4[g];                     // g == 32c here (invariant)
            nx2 = g4[g + 1];
        }
        int gend = 32 * (c + 1);
        while (g < gend && remaining >= 4) {
            cur = nxt; nxt = nx2;
            int gi = g + 2; if (gi > 127) gi = 127;
            nx2 = g4[gi];
            stepL(cur.x); stepL(cur.y); stepL(cur.z); stepL(cur.w);
            renorm();
            remaining -= 4; ++g;
        }
    }
    cur = nxt;                 // tail 0..3 steps (chunk 3, already published)
    if (remaining > 0) stepL(cur.x);
    if (remaining > 1) stepL(cur.y);
    if (remaining > 2) stepL(cur.z);

    int Ln = 2 * lab_lens[n] + 1;
    double last  = __shfl(beta, Ln - 1);
    double last2 = __shfl(beta, Ln - 2);
    double smv = last + last2;
    long long bb = __double_as_longlong(smv);
    int e = (int)(bb >> 52) - 1023;
    double mant = __longlong_as_double((bb & 0xFFFFFFFFFFFFFLL) | (1023LL << 52));
    if (s == 0)
        part[n] = (double)flog2((float)mant) + (double)(e + Mi);
}

// ---- final: Msum per n (f64, fixed order) + nll + deterministic sum ----
__global__ __launch_bounds__(1024) void final_kernel(const float* __restrict__ sumexp,
                                                     const int* __restrict__ in_lens,
                                                     const double* __restrict__ part,
                                                     float* __restrict__ out) {
    int tid = threadIdx.x;
    int v = tid >> 6, lane = tid & 63;     // 16 waves, 2 samples each
    __shared__ float nl[NN];
    #pragma unroll
    for (int k = 0; k < 2; ++k) {
        int n = v * 2 + k;
        int Tin = in_lens[n];
        double ms = 0.0;
        for (int t = lane; t < Tin; t += 64)
            ms += (double)flog2(sumexp[(size_t)t * NN + n]);
        #pragma unroll
        for (int off = 32; off; off >>= 1) ms += __shfl_xor(ms, off);
        if (lane == 0) nl[n] = (float)(-(part[n] - ms) * LN2);
    }
    __syncthreads();
    if (tid == 0) {
        float t = 0.f;
        for (int i = 0; i < NN; ++i) t += nl[i];
        out[0] = t;
    }
}

extern "C" void kernel_launch(void* const* d_in, const int* in_sizes, int n_in,
                              void* d_out, int out_size, void* d_ws, size_t ws_size,
                              hipStream_t stream) {
    const float* feats        = (const float*)d_in[0];
    const float* W            = (const float*)d_in[1];
    const int*   labeling     = (const int*)d_in[2];
    const int*   logit_lgts   = (const int*)d_in[3];
    const int*   labeling_lgts= (const int*)d_in[4];
    float* out = (float*)d_out;
    char* ws = (char*)d_ws;

    size_t off = 0;
    f16*   wt     = (f16*)(ws + off);   off += (size_t)CP * DD * 2;        // 1.44 MB
    f16*   fn     = (f16*)(ws + off);   off += (size_t)TT * NN * DD * 2;   // 16.8 MB
    float* sumexp = (float*)(ws + off); off += (size_t)TT * NN * 4;        // 64 KB
    float* lp_lab = (float*)(ws + off); off += (size_t)NN * 31 * TT * 4;   // 2.0 MB
    double* part  = (double*)(ws + off); off += NN * 8;

    prep_kernel<<<PREP_WBLK + PREP_ZBLK + PREP_FBLK, 256, 0, stream>>>(
        W, feats, wt, fn, sumexp);
    mega_kernel<<<MEGA_BLK, 256, 0, stream>>>(fn, wt, labeling, logit_lgts,
                                              labeling_lgts, sumexp, lp_lab, part);
    final_kernel<<<1, 1024, 0, stream>>>(sumexp, logit_lgts, part, out);

    (void)in_sizes; (void)n_in; (void)out_size; (void)ws_size;
}

// Round 7
// 154.208 us; speedup vs baseline: 1.0577x; 1.0577x over previous
//
#include <hip/hip_runtime.h>
#include <stdint.h>
#include <stddef.h>

// RadialCTC: cosine logits (norm_scale=32) -> log_softmax -> CTC(sum).
// Strategy: never materialize the (16384 x 1296) logits. GEMM (f16 MFMA)
// computes per-row sum(exp(logit)) fused in the epilogue; label log-probs via
// small f16 MFMA gather-GEMM; CTC alpha recursion one wave per sample.
// R9: linear f64 + pow2 renorm ctc. R11: XOR channel-slot LDS swizzle (gemm).
// R12: 9 -> 4 dispatches: NO CHANGE -> per-node gap ~= 0.
// R14: log2(sumexp) factored out (Msum); gather independent of gemm (-2us).
// R15 FAILED (312us): agent-scope acquire spin -> buffer_inv storms killed L2.
// R16 (159us): per-sample gather+ctc fused in-block; mega 62.6us.
// R17 (163us): register-direct gather + 4-chunk pipeline; mega 66.7us.
//   Post-mortem: R14's gemm+gather < 43.6us; adding ctc -> 62-67us. The tail
//   IS the f64 ctc chain (~60cyc/step dependent latency + 20cyc/step renorm,
//   inflated by contention with co-resident gemm waves).
// R18 (this round): attack the chain. (a) fused 2-step transition:
//   beta'' = P2*(c0*b + c1*b1 + c2*b2 + c3*b3 + c4*b4), coefficients off-chain
//   (c0=q, c1=q+q1, c2=k(q+q2)+q1, c3=k1*q1+k*q2, c4=k*k2*q2, q=2^lp1);
//   on-chain = 4 DPP shifts + FMA tree ~= 1.4x. (b) renorm every 8 steps
//   (growth <= 2^386 < 2^1023, exact pow2 -> correctness unchanged).
//   (c) s_setprio(1) around the chain (T5: latency-critical wave among
//   throughput waves). (d) 3-pair lp prefetch. Gather/gemm/prep unchanged.

typedef _Float16 f16;
typedef _Float16 f16x8 __attribute__((ext_vector_type(8)));
typedef float f32x4 __attribute__((ext_vector_type(4)));
typedef __attribute__((address_space(1))) void* as1_void_ptr;
typedef __attribute__((address_space(3))) void* as3_void_ptr;

#define TT 512
#define NN 32
#define CC 1296
#define DD 512
#define SS 30
#define CP 1408   // C padded to 11*128 for GEMM tiling (pad rows are zero)
#define LL 61     // 2*S+1 CTC states
#define NORM_SCALE 32.0f
#define LOG2E 1.4426950408889634f
#define LN2   0.6931471805599453f

#define PREP_WBLK (CP / 16)            // 88 c-tiles of 16 (covers pad -> zeros)
#define PREP_ZBLK 16                   // 16 blocks zero sumexp
#define PREP_FBLK (TT * NN / 4)        // 4096 fnorm blocks (4 rows each)

#define GEMM_BLK ((TT * NN / 128) * (CP / 128))   // 128*11 = 1408
#define MEGA_GC  NN                                // 32 gather+ctc blocks
#define MEGA_BLK (MEGA_GC + GEMM_BLK)              // 1440

__device__ __forceinline__ float fexp2(float x) { return __builtin_amdgcn_exp2f(x); }
__device__ __forceinline__ float flog2(float x) { return __builtin_amdgcn_logf(x); }

// whole-wave shift-right-by-1 of a double (two 32-bit DPPs, ctrl 0x138 =
// WAVE_SHR1). Lane 0 receives +0.0.
__device__ __forceinline__ double dpp_sr1_zero64(double x) {
    long long b = __double_as_longlong(x);
    int lo = (int)(b & 0xFFFFFFFFLL);
    int hi = (int)(b >> 32);
    int lo2 = __builtin_amdgcn_update_dpp(0, lo, 0x138, 0xF, 0xF, false);
    int hi2 = __builtin_amdgcn_update_dpp(0, hi, 0x138, 0xF, 0xF, false);
    return __longlong_as_double(((long long)hi2 << 32) |
                                (unsigned long long)(unsigned int)lo2);
}
// one level of DPP row-shr int max (identity 0; operands are >=0 hi-words)
template <int CTRL>
__device__ __forceinline__ int dpp_imax_level(int m) {
    int t = __builtin_amdgcn_update_dpp(0, m, CTRL, 0xF, 0xF, false);
    return m > t ? m : t;
}

// ---- fused prep: W column-norm + transpose to f16 (atomic-free, per-block
//      column ownership), feats row-normalize -> f16, sumexp zeroing. ----
__global__ __launch_bounds__(256) void prep_kernel(const float* __restrict__ W,
                                                   const float* __restrict__ feats,
                                                   f16* __restrict__ wt,
                                                   f16* __restrict__ fn,
                                                   float* __restrict__ sumexp) {
    int bx = blockIdx.x, tid = threadIdx.x;
    if (bx < PREP_WBLK) {
        // ---- W-prep: this block owns 16 columns c0..c0+15 ----
        __shared__ float red[256];
        __shared__ float rqs[16];
        int c0 = bx * 16;
        int cl = tid & 15, dg = tid >> 4;
        int c = c0 + cl;
        float ss = 0.f;
        if (c < CC) {
            for (int d = dg; d < DD; d += 16) {
                float v = W[(size_t)d * CC + c];
                ss += v * v;
            }
        }
        red[tid] = ss;
        __syncthreads();
        if (tid < 16) {
            float s2 = 0.f;
            #pragma unroll
            for (int k = 0; k < 16; ++k) s2 += red[tid + 16 * k];
            rqs[tid] = rsqrtf(s2);
        }
        __syncthreads();
        // write wt[c][d] (f16), 16 consecutive-d lanes per c; W re-reads hit L1
        int c_loc = tid >> 4, dl = tid & 15;
        int cc = c0 + c_loc;
        float rq = rqs[c_loc];
        #pragma unroll 4
        for (int it = 0; it < 32; ++it) {
            int d = dl + it * 16;
            float v = (cc < CC) ? W[(size_t)d * CC + cc] * rq : 0.f;
            wt[(size_t)cc * DD + d] = (f16)v;
        }
    } else if (bx < PREP_WBLK + PREP_ZBLK) {
        int zb = bx - PREP_WBLK;
        float4 z = {0.f, 0.f, 0.f, 0.f};
        ((float4*)sumexp)[zb * 256 + tid] = z;   // 16*256*16B = 64KB
    } else {
        // ---- fnorm: one wave per feats row ----
        int fb = bx - PREP_WBLK - PREP_ZBLK;
        int wv = (fb * 256 + tid) >> 6;  // row id, 0..16383
        int lane = tid & 63;
        const float4* src = (const float4*)(feats + (size_t)wv * DD) + lane * 2;
        float4 a = src[0], b = src[1];
        float ss = a.x*a.x + a.y*a.y + a.z*a.z + a.w*a.w
                 + b.x*b.x + b.y*b.y + b.z*b.z + b.w*b.w;
        #pragma unroll
        for (int off = 32; off; off >>= 1) ss += __shfl_xor(ss, off);
        float r = rsqrtf(ss);
        f16x8 o;
        o[0]=(f16)(a.x*r); o[1]=(f16)(a.y*r); o[2]=(f16)(a.z*r); o[3]=(f16)(a.w*r);
        o[4]=(f16)(b.x*r); o[5]=(f16)(b.y*r); o[6]=(f16)(b.z*r); o[7]=(f16)(b.w*r);
        *(f16x8*)(fn + (size_t)wv * DD + lane * 8) = o;
    }
}

// ---- gather wave (register-direct, barrier-free kb loop): computes its NT
//      16-row t-tiles of lp for each of 4 chunks, barrier after each chunk.
//      MFMA frag layout: A row=lane&15, k=(lane>>4)*8+e -> direct 16B loads. ----
template <int NT>
__device__ __forceinline__ void gather_wave(const f16* __restrict__ A,
                                            const f16* __restrict__ B,
                                            const int* __restrict__ labels,
                                            float* __restrict__ lp_lab,
                                            int n, int rbase, int lane) {
    int lm = lane & 15, hi = lane >> 4;
    int cls0 = (lm == 0) ? 0 : labels[n * SS + lm - 1];       // j = lm
    int cls1 = (lm >= 15) ? 0 : labels[n * SS + lm + 15];     // j = 16+lm
    const f16* pb0 = B + (size_t)cls0 * DD + hi * 8;
    const f16* pb1 = B + (size_t)cls1 * DD + hi * 8;
    const f16* pa0 = A + ((size_t)(rbase + lm) * NN + n) * DD + hi * 8;
    for (int c = 0; c < 4; ++c) {
        f32x4 acc[NT][2];
        #pragma unroll
        for (int i = 0; i < NT; ++i) {
            acc[i][0] = (f32x4){0.f, 0.f, 0.f, 0.f};
            acc[i][1] = (f32x4){0.f, 0.f, 0.f, 0.f};
        }
        const f16* pac = pa0 + (size_t)c * 128 * NN * DD;
        for (int kb = 0; kb < 16; ++kb) {
            f16x8 bf0 = *(const f16x8*)(pb0 + kb * 32);
            f16x8 bf1 = *(const f16x8*)(pb1 + kb * 32);
            #pragma unroll
            for (int i = 0; i < NT; ++i) {
                f16x8 af = *(const f16x8*)(pac + (size_t)(i * 16) * NN * DD + kb * 32);
                acc[i][0] = __builtin_amdgcn_mfma_f32_16x16x32_f16(af, bf0, acc[i][0], 0, 0, 0);
                acc[i][1] = __builtin_amdgcn_mfma_f32_16x16x32_f16(af, bf1, acc[i][1], 0, 0, 0);
            }
        }
        // raw scaled logits (no ls2: factored into final Msum); C/D row=hi*4+r
        #pragma unroll
        for (int i = 0; i < NT; ++i) {
            #pragma unroll
            for (int jn = 0; jn < 2; ++jn) {
                int jc = jn * 16 + lm;
                if (jc >= 31) continue;
                float4 o;
                o.x = acc[i][jn][0] * (NORM_SCALE * LOG2E);
                o.y = acc[i][jn][1] * (NORM_SCALE * LOG2E);
                o.z = acc[i][jn][2] * (NORM_SCALE * LOG2E);
                o.w = acc[i][jn][3] * (NORM_SCALE * LOG2E);
                *(float4*)&lp_lab[((size_t)n * 31 + jc) * TT
                                  + c * 128 + rbase + i * 16 + hi * 4] = o;
            }
        }
        __syncthreads();   // publish chunk c (barrier c)
    }
}

// ---- mega: blocks 0..31 = chunk-pipelined gather(waves1-3)+ctc(wave0);
//      blocks 32..1439 = gemm+sumexp (16KB LDS, XOR channel-slot swizzle). ----
__global__ __launch_bounds__(256) void mega_kernel(const f16* __restrict__ A,
                                                   const f16* __restrict__ B,
                                                   const int* __restrict__ labels,
                                                   const int* __restrict__ in_lens,
                                                   const int* __restrict__ lab_lens,
                                                   float* __restrict__ sumexp,
                                                   float* __restrict__ lp_lab,
                                                   double* __restrict__ part) {
    __shared__ __align__(16) f16 sm[8192];   // 16 KB (gemm only)
    int bx = blockIdx.x;
    int tid = threadIdx.x;
    int w = tid >> 6, lane = tid & 63;
    int lm = lane & 15, hi = lane >> 4;
    int sw = (lm >> 1) & 3;                // fragment-read channel swizzle

    if (bx >= MEGA_GC) {
        // ================= GEMM section (identical math since R14) ==========
        int j = bx - MEGA_GC;
        int bm = j & 127, bn = j >> 7;         // 1408 = 128 * 11
        int wm = w >> 1, wn = w & 1;           // 2x2 wave grid -> 64x64 per wave
        f32x4 acc[4][4];
        f32x4 zero = {0.f, 0.f, 0.f, 0.f};
        #pragma unroll
        for (int i = 0; i < 4; ++i)
            #pragma unroll
            for (int jj = 0; jj < 4; ++jj) acc[i][jj] = zero;

        for (int kb = 0; kb < 16; ++kb) {      // K=512, BK=32 (one MFMA K-step)
            #pragma unroll
            for (int p = 0; p < 2; ++p) {
                int s = p * 256 + tid;         // segment id, 16B each; 512 segs/tile
                int row = s >> 2;
                int ch = (s & 3) ^ ((row >> 1) & 3);   // swizzled source channel
                const f16* ga = A + (size_t)(bm * 128 + row) * DD + kb * 32 + ch * 8;
                const f16* gb = B + (size_t)(bn * 128 + row) * DD + kb * 32 + ch * 8;
                // LDS dest = wave-uniform base + lane*16 (contiguous, required)
                __builtin_amdgcn_global_load_lds((as1_void_ptr)ga,
                    (as3_void_ptr)&sm[(p * 256 + w * 64) * 8], 16, 0, 0);
                __builtin_amdgcn_global_load_lds((as1_void_ptr)gb,
                    (as3_void_ptr)&sm[4096 + (p * 256 + w * 64) * 8], 16, 0, 0);
            }
            __syncthreads();
            f16x8 af[4], bf[4];
            #pragma unroll
            for (int i = 0; i < 4; ++i)
                af[i] = *(const f16x8*)&sm[(wm * 64 + i * 16 + lm) * 32 + (hi ^ sw) * 8];
            #pragma unroll
            for (int jj = 0; jj < 4; ++jj)
                bf[jj] = *(const f16x8*)&sm[4096 + (wn * 64 + jj * 16 + lm) * 32 + (hi ^ sw) * 8];
            #pragma unroll
            for (int i = 0; i < 4; ++i)
                #pragma unroll
                for (int jj = 0; jj < 4; ++jj)
                    acc[i][jj] = __builtin_amdgcn_mfma_f32_16x16x32_f16(af[i], bf[jj], acc[i][jj], 0, 0, 0);
            __syncthreads();
        }
        // epilogue: per-row sum of exp(32*logit) over this block's 128 columns
        #pragma unroll
        for (int i = 0; i < 4; ++i) {
            float rs[4] = {0.f, 0.f, 0.f, 0.f};
            #pragma unroll
            for (int jj = 0; jj < 4; ++jj) {
                int c = bn * 128 + wn * 64 + jj * 16 + lm;   // C/D: col = lane&15
                bool ok = (c < CC);
                #pragma unroll
                for (int r = 0; r < 4; ++r)
                    rs[r] += ok ? fexp2(acc[i][jj][r] * (NORM_SCALE * LOG2E)) : 0.f;
            }
            #pragma unroll
            for (int off = 1; off < 16; off <<= 1) {        // sum over 16 cols
                #pragma unroll
                for (int r = 0; r < 4; ++r) rs[r] += __shfl_xor(rs[r], off);
            }
            if (lm == 0) {
                int rowb = bm * 128 + wm * 64 + i * 16 + hi * 4;  // row = quad*4+reg
                #pragma unroll
                for (int r = 0; r < 4; ++r) atomicAdd(&sumexp[rowb + r], rs[r]);
            }
        }
        return;
    }

    // ================= gather + ctc section (block n = bx) ==================
    int n = bx;
    if (w > 0) {
        // waves 1-3: produce lp chunks (48/48/32 t-rows per chunk), 4 barriers
        if (w < 3) gather_wave<3>(A, B, labels, lp_lab, n, (w - 1) * 48, lane);
        else       gather_wave<2>(A, B, labels, lp_lab, n, 96, lane);
        return;
    }

    // wave 0: ctc, pipelined one chunk behind the producers (4 barriers).
    // Fused 2-step transitions; renorm every 8 steps; setprio(1) on chain.
    int s = lane;            // 64 lanes; states 0..60 valid
    bool valid = s < LL;
    int ext = (valid && (s & 1)) ? labels[n * SS + (s >> 1)] : 0;
    int jmap = (valid && (s & 1)) ? ((s >> 1) + 1) : 0;   // state -> class slot
    int ext2 = __shfl_up(ext, 2);
    double skipd = ((s >= 2) && valid && (ext != ext2)) ? 1.0 : 0.0;
    double sk1 = dpp_sr1_zero64(skipd);     // k[s-1]
    double sk2 = dpp_sr1_zero64(sk1);       // k[s-2]
    double kk2 = skipd * sk2;               // k[s]*k[s-2]
    int Tin = in_lens[n];    // wave-uniform; freeze == stop at t = Tin-1
    const float4* g4 = (const float4*)(lp_lab + ((size_t)n * 31 + jmap) * TT);

    double beta = 0.0;
    int Mi = 0;              // running log2 scale: alpha_raw = log2(beta) + Mi

    auto stepL = [&](float lp) {            // single step (prologue/tail)
        double P = (double)fexp2(lp);       // |lp| <= ~46.2: f32-safe
        double b1 = dpp_sr1_zero64(beta);
        double b2 = dpp_sr1_zero64(b1);
        beta = (beta + b1 + b2 * skipd) * P;
    };
    // fused 2 steps: beta'' = P2*(c0*b + c1*b1 + c2*b2 + c3*b3 + c4*b4);
    // coefficients are OFF the beta dependency chain.
    auto step2 = [&](float lp1, float lp2) {
        double q  = (double)fexp2(lp1);
        double P2 = (double)fexp2(lp2);
        double q1 = dpp_sr1_zero64(q);
        double q2 = dpp_sr1_zero64(q1);
        double c1 = q + q1;
        double c2 = fma(skipd, q + q2, q1);
        double c3 = fma(sk1, q1, skipd * q2);
        double c4 = kk2 * q2;
        double b1 = dpp_sr1_zero64(beta);
        double b2 = dpp_sr1_zero64(b1);
        double b3 = dpp_sr1_zero64(b2);
        double b4 = dpp_sr1_zero64(b3);
        double u = fma(c1, b1, q * beta);
        double v = fma(c3, b3, c2 * b2);
        beta = (u + fma(c4, b4, v)) * P2;
    };
    auto renorm = [&]() {
        int h = (int)(__double_as_longlong(beta) >> 32);  // beta>=0: monotone
        h = dpp_imax_level<0x111>(h);        // row_shr:1
        h = dpp_imax_level<0x112>(h);        // row_shr:2
        h = dpp_imax_level<0x114>(h);        // row_shr:4
        h = dpp_imax_level<0x118>(h);        // row_shr:8 -> row max 15/31/47/63
        int r0 = __builtin_amdgcn_readlane(h, 15);
        int r1 = __builtin_amdgcn_readlane(h, 31);
        int r2 = __builtin_amdgcn_readlane(h, 47);
        int r3 = __builtin_amdgcn_readlane(h, 63);
        int mx = max(max(r0, r1), max(r2, r3));
        int e11 = mx >> 20;                  // biased 11-bit exponent
        double scale = __longlong_as_double((long long)(2046 - e11) << 52);
        beta *= scale;
        Mi += e11 - 1023;
    };

    __builtin_amdgcn_s_setprio(1);
    __syncthreads();         // barrier 0: chunk 0 (t=0..127) published
    float4 a0 = g4[0], a1 = g4[1];
    float4 pc0 = g4[2], pc1 = g4[3];
    float4 pn0 = g4[4], pn1 = g4[5];
    beta = (s <= 1) ? (double)fexp2(a0.x) : 0.0;

    // prologue: t = 1..7 (Tin >= 481, always full); growth <= 2^382: safe
    stepL(a0.y); stepL(a0.z); stepL(a0.w);
    stepL(a1.x); stepL(a1.y); stepL(a1.z); stepL(a1.w);
    renorm();
    int remaining = Tin - 8;   // steps done: 7 of Tin-1
    int g = 2;                 // next group (4 steps each); pc = groups g,g+1
    // chunk c covers groups [32c, 32c+32); chunks 0..2 always complete.
    // Prefetched pairs that cross a chunk boundary are ALWAYS discarded
    // (pc/pn reloaded fresh after each barrier) -> stale reads harmless.
    for (int c = 0; c < 4; ++c) {
        if (c > 0) {
            __syncthreads();                 // barrier c: chunk c published
            pc0 = g4[g];     pc1 = g4[g + 1];
            pn0 = g4[g + 2]; pn1 = g4[g + 3];
        }
        int gend = 32 * (c + 1);
        while (g + 2 <= gend && remaining >= 8) {
            int i0 = g + 4 > 127 ? 127 : g + 4;
            int i1 = g + 5 > 127 ? 127 : g + 5;
            float4 pp0 = g4[i0], pp1 = g4[i1];
            step2(pc0.x, pc0.y); step2(pc0.z, pc0.w);
            step2(pc1.x, pc1.y); step2(pc1.z, pc1.w);
            renorm();                        // every 8 steps: growth <= 2^386
            pc0 = pn0; pc1 = pn1; pn0 = pp0; pn1 = pp1;
            remaining -= 8; g += 2;
        }
    }
    // tail: 0..7 steps from pc (groups g, g+1; chunk 3 already published)
    if (remaining > 0) stepL(pc0.x);
    if (remaining > 1) stepL(pc0.y);
    if (remaining > 2) stepL(pc0.z);
    if (remaining > 3) stepL(pc0.w);
    if (remaining > 4) stepL(pc1.x);
    if (remaining > 5) stepL(pc1.y);
    if (remaining > 6) stepL(pc1.z);
    __builtin_amdgcn_s_setprio(0);

    int Ln = 2 * lab_lens[n] + 1;
    double last  = __shfl(beta, Ln - 1);
    double last2 = __shfl(beta, Ln - 2);
    double smv = last + last2;
    long long bb = __double_as_longlong(smv);
    int e = (int)(bb >> 52) - 1023;
    double mant = __longlong_as_double((bb & 0xFFFFFFFFFFFFFLL) | (1023LL << 52));
    if (s == 0)
        part[n] = (double)flog2((float)mant) + (double)(e + Mi);
}

// ---- final: Msum per n (f64, fixed order) + nll + deterministic sum ----
__global__ __launch_bounds__(1024) void final_kernel(const float* __restrict__ sumexp,
                                                     const int* __restrict__ in_lens,
                                                     const double* __restrict__ part,
                                                     float* __restrict__ out) {
    int tid = threadIdx.x;
    int v = tid >> 6, lane = tid & 63;     // 16 waves, 2 samples each
    __shared__ float nl[NN];
    #pragma unroll
    for (int k = 0; k < 2; ++k) {
        int n = v * 2 + k;
        int Tin = in_lens[n];
        double ms = 0.0;
        for (int t = lane; t < Tin; t += 64)
            ms += (double)flog2(sumexp[(size_t)t * NN + n]);
        #pragma unroll
        for (int off = 32; off; off >>= 1) ms += __shfl_xor(ms, off);
        if (lane == 0) nl[n] = (float)(-(part[n] - ms) * LN2);
    }
    __syncthreads();
    if (tid == 0) {
        float t = 0.f;
        for (int i = 0; i < NN; ++i) t += nl[i];
        out[0] = t;
    }
}

extern "C" void kernel_launch(void* const* d_in, const int* in_sizes, int n_in,
                              void* d_out, int out_size, void* d_ws, size_t ws_size,
                              hipStream_t stream) {
    const float* feats        = (const float*)d_in[0];
    const float* W            = (const float*)d_in[1];
    const int*   labeling     = (const int*)d_in[2];
    const int*   logit_lgts   = (const int*)d_in[3];
    const int*   labeling_lgts= (const int*)d_in[4];
    float* out = (float*)d_out;
    char* ws = (char*)d_ws;

    size_t off = 0;
    f16*   wt     = (f16*)(ws + off);   off += (size_t)CP * DD * 2;        // 1.44 MB
    f16*   fn     = (f16*)(ws + off);   off += (size_t)TT * NN * DD * 2;   // 16.8 MB
    float* sumexp = (float*)(ws + off); off += (size_t)TT * NN * 4;        // 64 KB
    float* lp_lab = (float*)(ws + off); off += (size_t)NN * 31 * TT * 4;   // 2.0 MB
    double* part  = (double*)(ws + off); off += NN * 8;

    prep_kernel<<<PREP_WBLK + PREP_ZBLK + PREP_FBLK, 256, 0, stream>>>(
        W, feats, wt, fn, sumexp);
    mega_kernel<<<MEGA_BLK, 256, 0, stream>>>(fn, wt, labeling, logit_lgts,
                                              labeling_lgts, sumexp, lp_lab, part);
    final_kernel<<<1, 1024, 0, stream>>>(sumexp, logit_lgts, part, out);

    (void)in_sizes; (void)n_in; (void)out_size; (void)ws_size;
}

// Round 8
// 153.156 us; speedup vs baseline: 1.0649x; 1.0069x over previous
//
#include <hip/hip_runtime.h>
#include <stdint.h>
#include <stddef.h>

// RadialCTC: cosine logits (norm_scale=32) -> log_softmax -> CTC(sum).
// Strategy: never materialize the (16384 x 1296) logits. GEMM (f16 MFMA)
// computes per-row sum(exp(logit)) fused in the epilogue; label log-probs via
// small f16 MFMA gather-GEMM; CTC alpha recursion one wave per sample.
// R9: linear f64 + pow2 renorm ctc. R11: XOR channel-slot LDS swizzle (gemm).
// R12: 9 -> 4 dispatches: NO CHANGE -> per-node gap ~= 0.
// R14: log2(sumexp) factored out (Msum); gather independent of gemm (-2us).
// R15 FAILED (312us): agent-scope acquire spin -> buffer_inv storms killed L2.
// R16 (159us): per-sample gather+ctc fused in-block; mega 62.6us.
// R17 (163us): register-direct gather + 4-chunk pipeline; mega 66.7us.
// R18 (154.2us): fused 2-step chain + renorm/8 + setprio(1): mega 54.9 (-11.8,
//   matched prediction). mega = max(gc ~50-55, gemm ~44) -> gc still pole;
//   solo chain ~7-8us inflated ~6x by issue contention (~20 gemm waves/CU).
// R19 (this round):
//   chain: setprio(3) on ctc wave (hw max), setprio(2) on gather waves;
//     renorm every 16 steps via toggle (worst-case growth 765 bits < 1023,
//     decay -765 > -1074: provably safe; exact pow2 -> bit-identical).
//   gemm: XCD-aware remap x=j&7, bm=x*16+(rr&15), bn=rr>>4 -> per-XCD A
//     footprint 2MB + B 1.4MB < 4MB L2: converts ~360MB of L3 tile re-reads
//     into L2 hits (the 2-barrier/kb structure pays full memory latency
//     every K-step, so latency tier matters).

typedef _Float16 f16;
typedef _Float16 f16x8 __attribute__((ext_vector_type(8)));
typedef float f32x4 __attribute__((ext_vector_type(4)));
typedef __attribute__((address_space(1))) void* as1_void_ptr;
typedef __attribute__((address_space(3))) void* as3_void_ptr;

#define TT 512
#define NN 32
#define CC 1296
#define DD 512
#define SS 30
#define CP 1408   // C padded to 11*128 for GEMM tiling (pad rows are zero)
#define LL 61     // 2*S+1 CTC states
#define NORM_SCALE 32.0f
#define LOG2E 1.4426950408889634f
#define LN2   0.6931471805599453f

#define PREP_WBLK (CP / 16)            // 88 c-tiles of 16 (covers pad -> zeros)
#define PREP_ZBLK 16                   // 16 blocks zero sumexp
#define PREP_FBLK (TT * NN / 4)        // 4096 fnorm blocks (4 rows each)

#define GEMM_BLK ((TT * NN / 128) * (CP / 128))   // 128*11 = 1408
#define MEGA_GC  NN                                // 32 gather+ctc blocks
#define MEGA_BLK (MEGA_GC + GEMM_BLK)              // 1440

__device__ __forceinline__ float fexp2(float x) { return __builtin_amdgcn_exp2f(x); }
__device__ __forceinline__ float flog2(float x) { return __builtin_amdgcn_logf(x); }

// whole-wave shift-right-by-1 of a double (two 32-bit DPPs, ctrl 0x138 =
// WAVE_SHR1). Lane 0 receives +0.0.
__device__ __forceinline__ double dpp_sr1_zero64(double x) {
    long long b = __double_as_longlong(x);
    int lo = (int)(b & 0xFFFFFFFFLL);
    int hi = (int)(b >> 32);
    int lo2 = __builtin_amdgcn_update_dpp(0, lo, 0x138, 0xF, 0xF, false);
    int hi2 = __builtin_amdgcn_update_dpp(0, hi, 0x138, 0xF, 0xF, false);
    return __longlong_as_double(((long long)hi2 << 32) |
                                (unsigned long long)(unsigned int)lo2);
}
// one level of DPP row-shr int max (identity 0; operands are >=0 hi-words)
template <int CTRL>
__device__ __forceinline__ int dpp_imax_level(int m) {
    int t = __builtin_amdgcn_update_dpp(0, m, CTRL, 0xF, 0xF, false);
    return m > t ? m : t;
}

// ---- fused prep: W column-norm + transpose to f16 (atomic-free, per-block
//      column ownership), feats row-normalize -> f16, sumexp zeroing. ----
__global__ __launch_bounds__(256) void prep_kernel(const float* __restrict__ W,
                                                   const float* __restrict__ feats,
                                                   f16* __restrict__ wt,
                                                   f16* __restrict__ fn,
                                                   float* __restrict__ sumexp) {
    int bx = blockIdx.x, tid = threadIdx.x;
    if (bx < PREP_WBLK) {
        // ---- W-prep: this block owns 16 columns c0..c0+15 ----
        __shared__ float red[256];
        __shared__ float rqs[16];
        int c0 = bx * 16;
        int cl = tid & 15, dg = tid >> 4;
        int c = c0 + cl;
        float ss = 0.f;
        if (c < CC) {
            for (int d = dg; d < DD; d += 16) {
                float v = W[(size_t)d * CC + c];
                ss += v * v;
            }
        }
        red[tid] = ss;
        __syncthreads();
        if (tid < 16) {
            float s2 = 0.f;
            #pragma unroll
            for (int k = 0; k < 16; ++k) s2 += red[tid + 16 * k];
            rqs[tid] = rsqrtf(s2);
        }
        __syncthreads();
        // write wt[c][d] (f16), 16 consecutive-d lanes per c; W re-reads hit L1
        int c_loc = tid >> 4, dl = tid & 15;
        int cc = c0 + c_loc;
        float rq = rqs[c_loc];
        #pragma unroll 4
        for (int it = 0; it < 32; ++it) {
            int d = dl + it * 16;
            float v = (cc < CC) ? W[(size_t)d * CC + cc] * rq : 0.f;
            wt[(size_t)cc * DD + d] = (f16)v;
        }
    } else if (bx < PREP_WBLK + PREP_ZBLK) {
        int zb = bx - PREP_WBLK;
        float4 z = {0.f, 0.f, 0.f, 0.f};
        ((float4*)sumexp)[zb * 256 + tid] = z;   // 16*256*16B = 64KB
    } else {
        // ---- fnorm: one wave per feats row ----
        int fb = bx - PREP_WBLK - PREP_ZBLK;
        int wv = (fb * 256 + tid) >> 6;  // row id, 0..16383
        int lane = tid & 63;
        const float4* src = (const float4*)(feats + (size_t)wv * DD) + lane * 2;
        float4 a = src[0], b = src[1];
        float ss = a.x*a.x + a.y*a.y + a.z*a.z + a.w*a.w
                 + b.x*b.x + b.y*b.y + b.z*b.z + b.w*b.w;
        #pragma unroll
        for (int off = 32; off; off >>= 1) ss += __shfl_xor(ss, off);
        float r = rsqrtf(ss);
        f16x8 o;
        o[0]=(f16)(a.x*r); o[1]=(f16)(a.y*r); o[2]=(f16)(a.z*r); o[3]=(f16)(a.w*r);
        o[4]=(f16)(b.x*r); o[5]=(f16)(b.y*r); o[6]=(f16)(b.z*r); o[7]=(f16)(b.w*r);
        *(f16x8*)(fn + (size_t)wv * DD + lane * 8) = o;
    }
}

// ---- gather wave (register-direct, barrier-free kb loop): computes its NT
//      16-row t-tiles of lp for each of 4 chunks, barrier after each chunk.
//      MFMA frag layout: A row=lane&15, k=(lane>>4)*8+e -> direct 16B loads. ----
template <int NT>
__device__ __forceinline__ void gather_wave(const f16* __restrict__ A,
                                            const f16* __restrict__ B,
                                            const int* __restrict__ labels,
                                            float* __restrict__ lp_lab,
                                            int n, int rbase, int lane) {
    __builtin_amdgcn_s_setprio(2);         // feeds the latency-critical chain
    int lm = lane & 15, hi = lane >> 4;
    int cls0 = (lm == 0) ? 0 : labels[n * SS + lm - 1];       // j = lm
    int cls1 = (lm >= 15) ? 0 : labels[n * SS + lm + 15];     // j = 16+lm
    const f16* pb0 = B + (size_t)cls0 * DD + hi * 8;
    const f16* pb1 = B + (size_t)cls1 * DD + hi * 8;
    const f16* pa0 = A + ((size_t)(rbase + lm) * NN + n) * DD + hi * 8;
    for (int c = 0; c < 4; ++c) {
        f32x4 acc[NT][2];
        #pragma unroll
        for (int i = 0; i < NT; ++i) {
            acc[i][0] = (f32x4){0.f, 0.f, 0.f, 0.f};
            acc[i][1] = (f32x4){0.f, 0.f, 0.f, 0.f};
        }
        const f16* pac = pa0 + (size_t)c * 128 * NN * DD;
        for (int kb = 0; kb < 16; ++kb) {
            f16x8 bf0 = *(const f16x8*)(pb0 + kb * 32);
            f16x8 bf1 = *(const f16x8*)(pb1 + kb * 32);
            #pragma unroll
            for (int i = 0; i < NT; ++i) {
                f16x8 af = *(const f16x8*)(pac + (size_t)(i * 16) * NN * DD + kb * 32);
                acc[i][0] = __builtin_amdgcn_mfma_f32_16x16x32_f16(af, bf0, acc[i][0], 0, 0, 0);
                acc[i][1] = __builtin_amdgcn_mfma_f32_16x16x32_f16(af, bf1, acc[i][1], 0, 0, 0);
            }
        }
        // raw scaled logits (no ls2: factored into final Msum); C/D row=hi*4+r
        #pragma unroll
        for (int i = 0; i < NT; ++i) {
            #pragma unroll
            for (int jn = 0; jn < 2; ++jn) {
                int jc = jn * 16 + lm;
                if (jc >= 31) continue;
                float4 o;
                o.x = acc[i][jn][0] * (NORM_SCALE * LOG2E);
                o.y = acc[i][jn][1] * (NORM_SCALE * LOG2E);
                o.z = acc[i][jn][2] * (NORM_SCALE * LOG2E);
                o.w = acc[i][jn][3] * (NORM_SCALE * LOG2E);
                *(float4*)&lp_lab[((size_t)n * 31 + jc) * TT
                                  + c * 128 + rbase + i * 16 + hi * 4] = o;
            }
        }
        __syncthreads();   // publish chunk c (barrier c)
    }
    __builtin_amdgcn_s_setprio(0);
}

// ---- mega: blocks 0..31 = chunk-pipelined gather(waves1-3)+ctc(wave0);
//      blocks 32..1439 = gemm+sumexp (16KB LDS, XOR channel-slot swizzle,
//      XCD-aware bm grouping for L2 residency). ----
__global__ __launch_bounds__(256) void mega_kernel(const f16* __restrict__ A,
                                                   const f16* __restrict__ B,
                                                   const int* __restrict__ labels,
                                                   const int* __restrict__ in_lens,
                                                   const int* __restrict__ lab_lens,
                                                   float* __restrict__ sumexp,
                                                   float* __restrict__ lp_lab,
                                                   double* __restrict__ part) {
    __shared__ __align__(16) f16 sm[8192];   // 16 KB (gemm only)
    int bx = blockIdx.x;
    int tid = threadIdx.x;
    int w = tid >> 6, lane = tid & 63;
    int lm = lane & 15, hi = lane >> 4;
    int sw = (lm >> 1) & 3;                // fragment-read channel swizzle

    if (bx >= MEGA_GC) {
        // ================= GEMM section =================
        int j = bx - MEGA_GC;
        // XCD-aware remap: gemm block j lands on XCD (j+32)%8 == j%8. Give
        // XCD x the contiguous bm range [x*16, x*16+16) for ALL bn -> per-XCD
        // working set = 16 A-panels (2MB) + B (1.4MB) < 4MB L2.
        int x = j & 7, rr = j >> 3;            // rr in [0,176)
        int bm = x * 16 + (rr & 15);
        int bn = rr >> 4;                      // [0,11)
        int wm = w >> 1, wn = w & 1;           // 2x2 wave grid -> 64x64 per wave
        f32x4 acc[4][4];
        f32x4 zero = {0.f, 0.f, 0.f, 0.f};
        #pragma unroll
        for (int i = 0; i < 4; ++i)
            #pragma unroll
            for (int jj = 0; jj < 4; ++jj) acc[i][jj] = zero;

        for (int kb = 0; kb < 16; ++kb) {      // K=512, BK=32 (one MFMA K-step)
            #pragma unroll
            for (int p = 0; p < 2; ++p) {
                int s = p * 256 + tid;         // segment id, 16B each; 512 segs/tile
                int row = s >> 2;
                int ch = (s & 3) ^ ((row >> 1) & 3);   // swizzled source channel
                const f16* ga = A + (size_t)(bm * 128 + row) * DD + kb * 32 + ch * 8;
                const f16* gb = B + (size_t)(bn * 128 + row) * DD + kb * 32 + ch * 8;
                // LDS dest = wave-uniform base + lane*16 (contiguous, required)
                __builtin_amdgcn_global_load_lds((as1_void_ptr)ga,
                    (as3_void_ptr)&sm[(p * 256 + w * 64) * 8], 16, 0, 0);
                __builtin_amdgcn_global_load_lds((as1_void_ptr)gb,
                    (as3_void_ptr)&sm[4096 + (p * 256 + w * 64) * 8], 16, 0, 0);
            }
            __syncthreads();
            f16x8 af[4], bf[4];
            #pragma unroll
            for (int i = 0; i < 4; ++i)
                af[i] = *(const f16x8*)&sm[(wm * 64 + i * 16 + lm) * 32 + (hi ^ sw) * 8];
            #pragma unroll
            for (int jj = 0; jj < 4; ++jj)
                bf[jj] = *(const f16x8*)&sm[4096 + (wn * 64 + jj * 16 + lm) * 32 + (hi ^ sw) * 8];
            #pragma unroll
            for (int i = 0; i < 4; ++i)
                #pragma unroll
                for (int jj = 0; jj < 4; ++jj)
                    acc[i][jj] = __builtin_amdgcn_mfma_f32_16x16x32_f16(af[i], bf[jj], acc[i][jj], 0, 0, 0);
            __syncthreads();
        }
        // epilogue: per-row sum of exp(32*logit) over this block's 128 columns
        #pragma unroll
        for (int i = 0; i < 4; ++i) {
            float rs[4] = {0.f, 0.f, 0.f, 0.f};
            #pragma unroll
            for (int jj = 0; jj < 4; ++jj) {
                int c = bn * 128 + wn * 64 + jj * 16 + lm;   // C/D: col = lane&15
                bool ok = (c < CC);
                #pragma unroll
                for (int r = 0; r < 4; ++r)
                    rs[r] += ok ? fexp2(acc[i][jj][r] * (NORM_SCALE * LOG2E)) : 0.f;
            }
            #pragma unroll
            for (int off = 1; off < 16; off <<= 1) {        // sum over 16 cols
                #pragma unroll
                for (int r = 0; r < 4; ++r) rs[r] += __shfl_xor(rs[r], off);
            }
            if (lm == 0) {
                int rowb = bm * 128 + wm * 64 + i * 16 + hi * 4;  // row = quad*4+reg
                #pragma unroll
                for (int r = 0; r < 4; ++r) atomicAdd(&sumexp[rowb + r], rs[r]);
            }
        }
        return;
    }

    // ================= gather + ctc section (block n = bx) ==================
    int n = bx;
    if (w > 0) {
        // waves 1-3: produce lp chunks (48/48/32 t-rows per chunk), 4 barriers
        if (w < 3) gather_wave<3>(A, B, labels, lp_lab, n, (w - 1) * 48, lane);
        else       gather_wave<2>(A, B, labels, lp_lab, n, 96, lane);
        return;
    }

    // wave 0: ctc, pipelined one chunk behind the producers (4 barriers).
    // Fused 2-step transitions; renorm every 16 steps; setprio(3) on chain.
    int s = lane;            // 64 lanes; states 0..60 valid
    bool valid = s < LL;
    int ext = (valid && (s & 1)) ? labels[n * SS + (s >> 1)] : 0;
    int jmap = (valid && (s & 1)) ? ((s >> 1) + 1) : 0;   // state -> class slot
    int ext2 = __shfl_up(ext, 2);
    double skipd = ((s >= 2) && valid && (ext != ext2)) ? 1.0 : 0.0;
    double sk1 = dpp_sr1_zero64(skipd);     // k[s-1]
    double sk2 = dpp_sr1_zero64(sk1);       // k[s-2]
    double kk2 = skipd * sk2;               // k[s]*k[s-2]
    int Tin = in_lens[n];    // wave-uniform; freeze == stop at t = Tin-1
    const float4* g4 = (const float4*)(lp_lab + ((size_t)n * 31 + jmap) * TT);

    double beta = 0.0;
    int Mi = 0;              // running log2 scale: alpha_raw = log2(beta) + Mi

    auto stepL = [&](float lp) {            // single step (prologue/tail)
        double P = (double)fexp2(lp);       // |lp| <= ~46.2: f32-safe
        double b1 = dpp_sr1_zero64(beta);
        double b2 = dpp_sr1_zero64(b1);
        beta = (beta + b1 + b2 * skipd) * P;
    };
    // fused 2 steps: beta'' = P2*(c0*b + c1*b1 + c2*b2 + c3*b3 + c4*b4);
    // coefficients are OFF the beta dependency chain.
    auto step2 = [&](float lp1, float lp2) {
        double q  = (double)fexp2(lp1);
        double P2 = (double)fexp2(lp2);
        double q1 = dpp_sr1_zero64(q);
        double q2 = dpp_sr1_zero64(q1);
        double c1 = q + q1;
        double c2 = fma(skipd, q + q2, q1);
        double c3 = fma(sk1, q1, skipd * q2);
        double c4 = kk2 * q2;
        double b1 = dpp_sr1_zero64(beta);
        double b2 = dpp_sr1_zero64(b1);
        double b3 = dpp_sr1_zero64(b2);
        double b4 = dpp_sr1_zero64(b3);
        double u = fma(c1, b1, q * beta);
        double v = fma(c3, b3, c2 * b2);
        beta = (u + fma(c4, b4, v)) * P2;
    };
    auto renorm = [&]() {
        int h = (int)(__double_as_longlong(beta) >> 32);  // beta>=0: monotone
        h = dpp_imax_level<0x111>(h);        // row_shr:1
        h = dpp_imax_level<0x112>(h);        // row_shr:2
        h = dpp_imax_level<0x114>(h);        // row_shr:4
        h = dpp_imax_level<0x118>(h);        // row_shr:8 -> row max 15/31/47/63
        int r0 = __builtin_amdgcn_readlane(h, 15);
        int r1 = __builtin_amdgcn_readlane(h, 31);
        int r2 = __builtin_amdgcn_readlane(h, 47);
        int r3 = __builtin_amdgcn_readlane(h, 63);
        int mx = max(max(r0, r1), max(r2, r3));
        int e11 = mx >> 20;                  // biased 11-bit exponent
        double scale = __longlong_as_double((long long)(2046 - e11) << 52);
        beta *= scale;
        Mi += e11 - 1023;
    };

    __builtin_amdgcn_s_setprio(3);           // hw max: latency-critical wave
    __syncthreads();         // barrier 0: chunk 0 (t=0..127) published
    float4 a0 = g4[0], a1 = g4[1];
    float4 pc0 = g4[2], pc1 = g4[3];
    float4 pn0 = g4[4], pn1 = g4[5];
    beta = (s <= 1) ? (double)fexp2(a0.x) : 0.0;

    // prologue: t = 1..7 (Tin >= 481, always full)
    stepL(a0.y); stepL(a0.z); stepL(a0.w);
    stepL(a1.x); stepL(a1.y); stepL(a1.z); stepL(a1.w);
    renorm();
    int remaining = Tin - 8;   // steps done: 7 of Tin-1
    int g = 2;                 // next group (4 steps each); pc = groups g,g+1
    int rn = 0;                // renorm toggle: renorm every 2nd 8-step block
    // chunk c covers groups [32c, 32c+32); chunks 0..2 always complete.
    // Prefetched pairs crossing a chunk boundary are ALWAYS discarded (pc/pn
    // reloaded fresh after each barrier) -> stale reads harmless.
    // Max un-renormed span = 16 steps: pathological growth 16*47.8 = 765
    // bits < 1023; decay -765 > -1074. Renorm = exact pow2 -> bit-identical.
    for (int c = 0; c < 4; ++c) {
        if (c > 0) {
            __syncthreads();                 // barrier c: chunk c published
            pc0 = g4[g];     pc1 = g4[g + 1];
            pn0 = g4[g + 2]; pn1 = g4[g + 3];
        }
        int gend = 32 * (c + 1);
        while (g + 2 <= gend && remaining >= 8) {
            int i0 = g + 4 > 127 ? 127 : g + 4;
            int i1 = g + 5 > 127 ? 127 : g + 5;
            float4 pp0 = g4[i0], pp1 = g4[i1];
            step2(pc0.x, pc0.y); step2(pc0.z, pc0.w);
            step2(pc1.x, pc1.y); step2(pc1.z, pc1.w);
            rn ^= 1;
            if (!rn) renorm();               // every 16 steps
            pc0 = pn0; pc1 = pn1; pn0 = pp0; pn1 = pp1;
            remaining -= 8; g += 2;
        }
    }
    // tail: 0..7 steps from pc (groups g, g+1; chunk 3 already published);
    // max span since last renorm = 8 + 7 = 15 steps: safe.
    if (remaining > 0) stepL(pc0.x);
    if (remaining > 1) stepL(pc0.y);
    if (remaining > 2) stepL(pc0.z);
    if (remaining > 3) stepL(pc0.w);
    if (remaining > 4) stepL(pc1.x);
    if (remaining > 5) stepL(pc1.y);
    if (remaining > 6) stepL(pc1.z);
    __builtin_amdgcn_s_setprio(0);

    int Ln = 2 * lab_lens[n] + 1;
    double last  = __shfl(beta, Ln - 1);
    double last2 = __shfl(beta, Ln - 2);
    double smv = last + last2;
    long long bb = __double_as_longlong(smv);
    int e = (int)(bb >> 52) - 1023;
    double mant = __longlong_as_double((bb & 0xFFFFFFFFFFFFFLL) | (1023LL << 52));
    if (s == 0)
        part[n] = (double)flog2((float)mant) + (double)(e + Mi);
}

// ---- final: Msum per n (f64, fixed order) + nll + deterministic sum ----
__global__ __launch_bounds__(1024) void final_kernel(const float* __restrict__ sumexp,
                                                     const int* __restrict__ in_lens,
                                                     const double* __restrict__ part,
                                                     float* __restrict__ out) {
    int tid = threadIdx.x;
    int v = tid >> 6, lane = tid & 63;     // 16 waves, 2 samples each
    __shared__ float nl[NN];
    #pragma unroll
    for (int k = 0; k < 2; ++k) {
        int n = v * 2 + k;
        int Tin = in_lens[n];
        double ms = 0.0;
        for (int t = lane; t < Tin; t += 64)
            ms += (double)flog2(sumexp[(size_t)t * NN + n]);
        #pragma unroll
        for (int off = 32; off; off >>= 1) ms += __shfl_xor(ms, off);
        if (lane == 0) nl[n] = (float)(-(part[n] - ms) * LN2);
    }
    __syncthreads();
    if (tid == 0) {
        float t = 0.f;
        for (int i = 0; i < NN; ++i) t += nl[i];
        out[0] = t;
    }
}

extern "C" void kernel_launch(void* const* d_in, const int* in_sizes, int n_in,
                              void* d_out, int out_size, void* d_ws, size_t ws_size,
                              hipStream_t stream) {
    const float* feats        = (const float*)d_in[0];
    const float* W            = (const float*)d_in[1];
    const int*   labeling     = (const int*)d_in[2];
    const int*   logit_lgts   = (const int*)d_in[3];
    const int*   labeling_lgts= (const int*)d_in[4];
    float* out = (float*)d_out;
    char* ws = (char*)d_ws;

    size_t off = 0;
    f16*   wt     = (f16*)(ws + off);   off += (size_t)CP * DD * 2;        // 1.44 MB
    f16*   fn     = (f16*)(ws + off);   off += (size_t)TT * NN * DD * 2;   // 16.8 MB
    float* sumexp = (float*)(ws + off); off += (size_t)TT * NN * 4;        // 64 KB
    float* lp_lab = (float*)(ws + off); off += (size_t)NN * 31 * TT * 4;   // 2.0 MB
    double* part  = (double*)(ws + off); off += NN * 8;

    prep_kernel<<<PREP_WBLK + PREP_ZBLK + PREP_FBLK, 256, 0, stream>>>(
        W, feats, wt, fn, sumexp);
    mega_kernel<<<MEGA_BLK, 256, 0, stream>>>(fn, wt, labeling, logit_lgts,
                                              labeling_lgts, sumexp, lp_lab, part);
    final_kernel<<<1, 1024, 0, stream>>>(sumexp, logit_lgts, part, out);

    (void)in_sizes; (void)n_in; (void)out_size; (void)ws_size;
}